// Round 24
// baseline (116.154 us; speedup 1.0000x reference)
//
#include <hip/hip_runtime.h>

#define N_NODES 50000
#define E_EDGES 1600000
#define ETOT    (E_EDGES + N_NODES)
#define DIN  128
#define DOUT 128
#define NH   4
#define HD   32

typedef unsigned short ushort_t;
typedef unsigned int uint_t;
typedef __attribute__((ext_vector_type(8))) short bfrag;
typedef __attribute__((ext_vector_type(4))) float ffrag;

__device__ __forceinline__ ushort_t f2bf(float f) {
  uint_t u = __float_as_uint(f);
  u += 0x7fffu + ((u >> 16) & 1u);   // RNE
  return (ushort_t)(u >> 16);
}
__device__ __forceinline__ float bf_lo(uint_t u) {
  return __uint_as_float(u << 16);
}
__device__ __forceinline__ float bf_hi(uint_t u) {
  return __uint_as_float(u & 0xffff0000u);
}

// ---------------- CSR build params ----------------
#define BSZ   64
#define NBUCK ((N_NODES + BSZ - 1) / BSZ)       // 782
#define NBP   1024
#define CAP   2560
#define EPB_A 8192
#define NBLK_A ((ETOT + EPB_A - 1) / EPB_A)     // 202
#define NCHUNK 13
#define NTILE ((N_NODES + 63) / 64)             // 782 gemm tiles
#define TPB   3                                  // tiles per gemm block
#define GEMM_BLOCKS ((NTILE + TPB - 1) / TPB)   // 261

// packed edge word: p = (di<<16) | si (both < 2^16)

// x-prefetch for one tile into a register array (static indices only)
#define PREFETCH_X(dst, tile)                                          \
  {                                                                    \
    int nb_ = (tile) * 64 + wv * 16;                                   \
    int na_ = nb_ + lr;                                                \
    if (na_ >= N_NODES) na_ = N_NODES - 1;                             \
    const float* xr_ = x + (size_t)na_ * DIN;                          \
    _Pragma("unroll")                                                  \
    for (int kt_ = 0; kt_ < 4; kt_++) {                                \
      dst[kt_ * 2]     = *(const float4*)&xr_[kt_ * 32 + lg * 8];      \
      dst[kt_ * 2 + 1] = *(const float4*)&xr_[kt_ * 32 + lg * 8 + 4];  \
    }                                                                  \
  }

// full per-tile compute: MFMA + hb store + att-logit epilogue
#define COMPUTE_TILE(px, tile)                                               \
  {                                                                          \
    const int nbase_ = (tile) * 64 + wv * 16;                                \
    ffrag acc[8];                                                            \
    _Pragma("unroll")                                                        \
    for (int oc = 0; oc < 8; oc++) acc[oc] = (ffrag){0.f, 0.f, 0.f, 0.f};    \
    _Pragma("unroll")                                                        \
    for (int kt = 0; kt < 4; kt++) {                                         \
      const float4 x0 = px[kt * 2];                                          \
      const float4 x1 = px[kt * 2 + 1];                                      \
      bfrag a;                                                               \
      a[0] = (short)f2bf(x0.x); a[1] = (short)f2bf(x0.y);                    \
      a[2] = (short)f2bf(x0.z); a[3] = (short)f2bf(x0.w);                    \
      a[4] = (short)f2bf(x1.x); a[5] = (short)f2bf(x1.y);                    \
      a[6] = (short)f2bf(x1.z); a[7] = (short)f2bf(x1.w);                    \
      _Pragma("unroll")                                                      \
      for (int oc = 0; oc < 8; oc++) {                                       \
        const int u = ((oc * 16 + lr) << 4) + kt * 4 + lg;                   \
        const bfrag b = *(const bfrag*)&Ws[(u ^ (lr & 7)) * 8];              \
        acc[oc] = __builtin_amdgcn_mfma_f32_16x16x32_bf16(a, b, acc[oc],     \
                                                          0, 0, 0);          \
      }                                                                      \
    }                                                                        \
    _Pragma("unroll")                                                        \
    for (int oc = 0; oc < 8; oc++) {                                         \
      _Pragma("unroll")                                                      \
      for (int j = 0; j < 4; j++) {                                          \
        int n = nbase_ + lg * 4 + j;                                         \
        if (n < N_NODES)                                                     \
          hb[((size_t)n << 7) + oc * 16 + lr] = f2bf(acc[oc][j]);            \
      }                                                                      \
    }                                                                        \
    _Pragma("unroll")                                                        \
    for (int j = 0; j < 4; j++) {                                            \
      float ps[4] = {0.f, 0.f, 0.f, 0.f};                                    \
      float pd[4] = {0.f, 0.f, 0.f, 0.f};                                    \
      _Pragma("unroll")                                                      \
      for (int oc = 0; oc < 8; oc++) {                                       \
        ps[oc >> 1] = fmaf(acc[oc][j], asv[oc], ps[oc >> 1]);                \
        pd[oc >> 1] = fmaf(acc[oc][j], adv[oc], pd[oc >> 1]);                \
      }                                                                      \
      _Pragma("unroll")                                                      \
      for (int off = 1; off < 16; off <<= 1) {                               \
        _Pragma("unroll")                                                    \
        for (int hd = 0; hd < 4; hd++) {                                     \
          ps[hd] += __shfl_xor(ps[hd], off);                                 \
          pd[hd] += __shfl_xor(pd[hd], off);                                 \
        }                                                                    \
      }                                                                      \
      int n = nbase_ + lg * 4 + j;                                           \
      if (n < N_NODES && lr < 4) {                                           \
        float vs = lr == 0 ? ps[0] : lr == 1 ? ps[1] : lr == 2 ? ps[2] : ps[3]; \
        float vd = lr == 0 ? pd[0] : lr == 1 ? pd[1] : lr == 2 ? pd[2] : pd[3]; \
        a_src[n * NH + lr] = vs;                                             \
        a_dst[n * NH + lr] = vd;                                             \
      }                                                                      \
    }                                                                        \
  }

// ---------------- K1: role-split fused kernel ----------------
// blocks [0, NBLK_A): binA2 in-block counting sort (r22 proven)
// blocks [NBLK_A, +GEMM_BLOCKS): gemm_att, TPB tiles/block, W staged ONCE,
//   next tile's x prefetched before current tile's compute (reg dbuf).
__global__ __launch_bounds__(256, 4) void fused_binA_gemm_kernel(
    const int* __restrict__ ei, uint_t* __restrict__ ebuf,
    int* __restrict__ cntm, int* __restrict__ offm,
    const float* __restrict__ x, const float* __restrict__ W,
    const float* __restrict__ att_src, const float* __restrict__ att_dst,
    ushort_t* __restrict__ hb, float* __restrict__ a_src,
    float* __restrict__ a_dst) {
  __shared__ uint_t lds[EPB_A + NBP + 8];   // 36.9 KB, roles alias
  const int tid = threadIdx.x;

  if (blockIdx.x < NBLK_A) {
    // ---------- binA2 role (r22 proven) ----------
    uint_t* stage = lds;
    int* hist = (int*)(lds + EPB_A);
    int* wsum = hist + NBP;
    const int cb = blockIdx.x;
    const int e0 = cb * EPB_A;
    const int n = min(EPB_A, ETOT - e0);
    for (int i = tid; i < NBP; i += 256) hist[i] = 0;
    __syncthreads();
    for (int i = tid; i < n; i += 256) {
      int e = e0 + i;
      int si, di;
      if (e < E_EDGES) { si = ei[e]; di = ei[E_EDGES + e]; }
      else             { si = e - E_EDGES; di = si; }
      stage[i] = ((uint_t)di << 16) | (uint_t)si;
      atomicAdd(&hist[di >> 6], 1);
    }
    __syncthreads();
    const int ln = tid & 63, wv = tid >> 6;
    int c0 = hist[4 * tid], c1 = hist[4 * tid + 1];
    int c2 = hist[4 * tid + 2], c3 = hist[4 * tid + 3];
    int p1 = c0, p2 = c0 + c1, p3 = c0 + c1 + c2;
    int tot = p3 + c3;
    int xx = tot;
#pragma unroll
    for (int off = 1; off < 64; off <<= 1) {
      int y = __shfl_up(xx, off, 64);
      if (ln >= off) xx += y;
    }
    if (ln == 63) wsum[wv] = xx;
    __syncthreads();
    if (tid < 4) {
      int w = wsum[tid];
#pragma unroll
      for (int off = 1; off < 4; off <<= 1) {
        int y = __shfl_up(w, off, 64);
        if (tid >= off) w += y;
      }
      wsum[tid] = w;
    }
    __syncthreads();
    const int wo = (wv == 0) ? 0 : wsum[wv - 1];
    const int base = wo + xx - tot;
#pragma unroll
    for (int k = 0; k < 4; k++) {
      int idx = 4 * tid + k;
      int c = k == 0 ? c0 : k == 1 ? c1 : k == 2 ? c2 : c3;
      int o = base + (k == 0 ? 0 : k == 1 ? p1 : k == 2 ? p2 : p3);
      if (idx < NBUCK) {
        cntm[(size_t)cb * NBP + idx] = c;
        offm[(size_t)cb * NBP + idx] = o;
      }
      hist[idx] = o;
    }
    __syncthreads();
    for (int i = tid; i < n; i += 256) {
      uint_t p = stage[i];
      int pos = atomicAdd(&hist[p >> 22], 1);
      if (pos >= 0 && pos < n) ebuf[e0 + pos] = p;
    }
    return;
  }

  // ---------- gemm_att role: TPB tiles, W staged once, pipelined x ------
  ushort_t* Ws = (ushort_t*)lds;   // 32 KB bf16
  const int gb = blockIdx.x - NBLK_A;
  const int wv = tid >> 6, l = tid & 63;
  const int lr = l & 15, lg = l >> 4;
  const int t0 = gb * TPB;

  float4 pxA[8], pxB[8];
  PREFETCH_X(pxA, t0);   // tile 0 loads fly during W staging

  for (int u = tid; u < 2048; u += 256) {
    int row = u >> 4;
    float4 w0 = *(const float4*)&W[u * 8];
    float4 w1 = *(const float4*)&W[u * 8 + 4];
    uint4 pk;
    pk.x = (uint_t)f2bf(w0.x) | ((uint_t)f2bf(w0.y) << 16);
    pk.y = (uint_t)f2bf(w0.z) | ((uint_t)f2bf(w0.w) << 16);
    pk.z = (uint_t)f2bf(w1.x) | ((uint_t)f2bf(w1.y) << 16);
    pk.w = (uint_t)f2bf(w1.z) | ((uint_t)f2bf(w1.w) << 16);
    *(uint4*)&Ws[(u ^ (row & 7)) * 8] = pk;
  }
  __syncthreads();

  float asv[8], adv[8];
#pragma unroll
  for (int oc = 0; oc < 8; oc++) {
    asv[oc] = att_src[oc * 16 + lr];
    adv[oc] = att_dst[oc * 16 + lr];
  }

  // tile 0: prefetch tile1 first, then compute tile0
  if (t0 + 1 < NTILE) PREFETCH_X(pxB, t0 + 1);
  COMPUTE_TILE(pxA, t0);
  // tile 1
  if (t0 + 1 < NTILE) {
    if (t0 + 2 < NTILE) PREFETCH_X(pxA, t0 + 2);
    COMPUTE_TILE(pxB, t0 + 1);
  }
  // tile 2
  if (t0 + 2 < NTILE) {
    COMPUTE_TILE(pxA, t0 + 2);
  }
}

// ---------------- K2: per-bucket CSR build (r22 proven; ushort col) -------
__global__ __launch_bounds__(256) void binB_kernel(
    const uint_t* __restrict__ ebuf, const int* __restrict__ cntm,
    const int* __restrict__ offm,
    int* __restrict__ rs, int* __restrict__ re, ushort_t* __restrict__ col) {
  __shared__ uint_t el[CAP];
  __shared__ int cnt_l[BSZ * NCHUNK];
  __shared__ int roff_l[BSZ * NCHUNK];
  __shared__ int wsum[4];
  const int b = blockIdx.x;
  const int tid = threadIdx.x;
  const int ln = tid & 63, wv = tid >> 6;
  const int n0 = b << 6;
  const int nn = min(BSZ, N_NODES - n0);

  int c = (tid < NBLK_A) ? cntm[(size_t)tid * NBP + b] : 0;
  int o = (tid < NBLK_A) ? offm[(size_t)tid * NBP + b] : 0;
  int xx = c;
#pragma unroll
  for (int off = 1; off < 64; off <<= 1) {
    int y = __shfl_up(xx, off, 64);
    if (ln >= off) xx += y;
  }
  if (ln == 63) wsum[wv] = xx;
  __syncthreads();
  if (tid < 4) {
    int w = wsum[tid];
#pragma unroll
    for (int off = 1; off < 4; off <<= 1) {
      int y = __shfl_up(w, off, 64);
      if (tid >= off) w += y;
    }
    wsum[tid] = w;
  }
  __syncthreads();
  const int wo = (wv == 0) ? 0 : wsum[wv - 1];
  const int mystart = wo + xx - c;
  const int total0 = wsum[3];
  const int total = total0 < CAP ? total0 : CAP;
  if (tid < NBLK_A) {
    const uint_t* src = ebuf + (size_t)tid * EPB_A + o;
    for (int j = 0; j < c; j++) {
      int d = mystart + j;
      if (d < CAP) el[d] = src[j];
    }
  }
  for (int k = tid; k < BSZ * NCHUNK; k += 256) cnt_l[k] = 0;
  __syncthreads();

  for (int i = tid; i < total; i += 256) {
    uint_t p = el[i];
    int key = (int)((p >> 16) & 63) * NCHUNK + (int)((p & 0xFFFFu) >> 12);
    atomicAdd(&cnt_l[key], 1);
  }
  __syncthreads();
  if (tid < BSZ) {
    int pref[NCHUNK];
    int tot = 0;
#pragma unroll
    for (int k = 0; k < NCHUNK; k++) { pref[k] = tot; tot += cnt_l[tid * NCHUNK + k]; }
    int x2 = tot;
#pragma unroll
    for (int off = 1; off < 64; off <<= 1) {
      int y = __shfl_up(x2, off, 64);
      if (tid >= off) x2 += y;
    }
    const int nodebase = x2 - tot;
#pragma unroll
    for (int k = 0; k < NCHUNK; k++) roff_l[tid * NCHUNK + k] = nodebase + pref[k];
    if (tid < nn) {
      rs[n0 + tid] = b * CAP + nodebase;
      re[n0 + tid] = b * CAP + nodebase + tot;
    }
  }
  __syncthreads();
  for (int k = tid; k < BSZ * NCHUNK; k += 256) cnt_l[k] = 0;
  __syncthreads();
  for (int i = tid; i < total; i += 256) {
    uint_t p = el[i];
    int si = (int)(p & 0xFFFFu);
    int key = (int)((p >> 16) & 63) * NCHUNK + (si >> 12);
    int pos = atomicAdd(&cnt_l[key], 1);
    int q = b * CAP + roff_l[key] + pos;
    if (q >= 0 && q < NBUCK * CAP) col[q] = (ushort_t)si;
  }
}

// ---------------- K3: single-pass aggregation + prefetch (r22 proven) -----
#define NPB 16
#define CH  16

__global__ __launch_bounds__(256, 8) void agg_kernel(
    const ushort_t* __restrict__ col, const int* __restrict__ rs,
    const int* __restrict__ re, const ushort_t* __restrict__ hb,
    const float* __restrict__ a_src, const float* __restrict__ a_dst,
    float* __restrict__ out) {
  __shared__ float w_lds[NPB][CH][NH];
  __shared__ int   si_lds[NPB][CH];
  const int tid  = threadIdx.x;
  const int slot = tid >> 4;
  const int t    = tid & 15;
  const int node = blockIdx.x * NPB + slot;
  const int start = rs[node];
  const int deg   = re[node] - start;
  const float4 ad = *(const float4*)(a_dst + (size_t)node * NH);

  const int head = t >> 2;
  const int c8 = t << 3;
  const ushort_t* hc = hb + c8;
  float s = 0.f;
  float a0 = 0.f, a1 = 0.f, a2 = 0.f, a3 = 0.f;
  float a4 = 0.f, a5 = 0.f, a6 = 0.f, a7 = 0.f;
  float b0 = 0.f, b1 = 0.f, b2 = 0.f, b3 = 0.f;
  float b4 = 0.f, b5 = 0.f, b6 = 0.f, b7 = 0.f;

  int   si_c = 0;
  float4 as_c = make_float4(0.f, 0.f, 0.f, 0.f);
  if (t < deg) {
    si_c = col[start + t];
    si_c = si_c < N_NODES ? si_c : 0;
    as_c = *(const float4*)(a_src + (size_t)si_c * NH);
  }

  for (int base_e = 0; base_e < deg; base_e += CH) {
    int nch = deg - base_e;
    if (nch > CH) nch = CH;
    if (t < nch) {
      si_lds[slot][t] = si_c;
      float v0 = as_c.x + ad.x; v0 = v0 > 0.f ? v0 : 0.2f * v0;
      float v1 = as_c.y + ad.y; v1 = v1 > 0.f ? v1 : 0.2f * v1;
      float v2 = as_c.z + ad.z; v2 = v2 > 0.f ? v2 : 0.2f * v2;
      float v3 = as_c.w + ad.w; v3 = v3 > 0.f ? v3 : 0.2f * v3;
      w_lds[slot][t][0] = __expf(v0);
      w_lds[slot][t][1] = __expf(v1);
      w_lds[slot][t][2] = __expf(v2);
      w_lds[slot][t][3] = __expf(v3);
    }
    __builtin_amdgcn_fence(__ATOMIC_ACQ_REL, "wavefront");
    int nb = base_e + CH;
    if (nb + t < deg) {
      int sn = col[start + nb + t];
      sn = sn < N_NODES ? sn : 0;
      si_c = sn;
      as_c = *(const float4*)(a_src + (size_t)sn * NH);
    }
#pragma unroll 2
    for (int j = 0; j < nch; j++) {
      int si = si_lds[slot][j];
      float e = w_lds[slot][j][head];
      s += e;
      const uint4 hv = *(const uint4*)(hc + ((size_t)si << 7));
      float h0 = bf_lo(hv.x), h1 = bf_hi(hv.x);
      float h2 = bf_lo(hv.y), h3 = bf_hi(hv.y);
      float h4 = bf_lo(hv.z), h5 = bf_hi(hv.z);
      float h6 = bf_lo(hv.w), h7 = bf_hi(hv.w);
      a0 = fmaf(h0, e, a0); b0 += h0;
      a1 = fmaf(h1, e, a1); b1 += h1;
      a2 = fmaf(h2, e, a2); b2 += h2;
      a3 = fmaf(h3, e, a3); b3 += h3;
      a4 = fmaf(h4, e, a4); b4 += h4;
      a5 = fmaf(h5, e, a5); b5 += h5;
      a6 = fmaf(h6, e, a6); b6 += h6;
      a7 = fmaf(h7, e, a7); b7 += h7;
    }
    __builtin_amdgcn_fence(__ATOMIC_ACQ_REL, "wavefront");
  }
  const float inv = 1.0f / s;
  float* op = out + ((size_t)node << 7) + c8;
  *(float4*)(op)     = make_float4(fmaf(a0, inv, b0), fmaf(a1, inv, b1),
                                   fmaf(a2, inv, b2), fmaf(a3, inv, b3));
  *(float4*)(op + 4) = make_float4(fmaf(a4, inv, b4), fmaf(a5, inv, b5),
                                   fmaf(a6, inv, b6), fmaf(a7, inv, b7));
}

extern "C" void kernel_launch(void* const* d_in, const int* in_sizes, int n_in,
                              void* d_out, int out_size, void* d_ws, size_t ws_size,
                              hipStream_t stream) {
  const float* x       = (const float*)d_in[0];
  const int*   ei      = (const int*)d_in[1];
  const float* W       = (const float*)d_in[2];
  const float* att_src = (const float*)d_in[3];
  const float* att_dst = (const float*)d_in[4];
  float* out = (float*)d_out;

  // ws: hb | a_src | a_dst | cntm | offm | rs | re | col | ebuf
  ushort_t* hb = (ushort_t*)d_ws;
  float* a_src = (float*)(hb + (size_t)N_NODES * DOUT);
  float* a_dst = a_src + (size_t)N_NODES * NH;
  int* cntm    = (int*)(a_dst + (size_t)N_NODES * NH);    // NBLK_A*NBP
  int* offm    = cntm + (size_t)NBLK_A * NBP;             // NBLK_A*NBP
  int* rs      = offm + (size_t)NBLK_A * NBP;             // N_NODES
  int* re      = rs + N_NODES;                            // N_NODES
  ushort_t* col = (ushort_t*)(re + N_NODES);              // NBUCK*CAP
  uint_t* ebuf = (uint_t*)(col + (size_t)NBUCK * CAP);    // NBLK_A*EPB_A

  fused_binA_gemm_kernel<<<NBLK_A + GEMM_BLOCKS, 256, 0, stream>>>(
      ei, ebuf, cntm, offm, x, W, att_src, att_dst, hb, a_src, a_dst);
  binB_kernel<<<NBUCK, 256, 0, stream>>>(ebuf, cntm, offm, rs, re, col);
  agg_kernel<<<N_NODES / NPB, 256, 0, stream>>>(col, rs, re, hb, a_src, a_dst, out);
}

// Round 25
// 100.214 us; speedup vs baseline: 1.1591x; 1.1591x over previous
//
#include <hip/hip_runtime.h>

#define N_NODES 50000
#define E_EDGES 1600000
#define ETOT    (E_EDGES + N_NODES)
#define DIN  128
#define DOUT 128
#define NH   4
#define HD   32

typedef unsigned short ushort_t;
typedef unsigned int uint_t;
typedef __attribute__((ext_vector_type(8))) short bfrag;
typedef __attribute__((ext_vector_type(4))) float ffrag;

__device__ __forceinline__ ushort_t f2bf(float f) {
  uint_t u = __float_as_uint(f);
  u += 0x7fffu + ((u >> 16) & 1u);   // RNE
  return (ushort_t)(u >> 16);
}
__device__ __forceinline__ float bf_lo(uint_t u) {
  return __uint_as_float(u << 16);
}
__device__ __forceinline__ float bf_hi(uint_t u) {
  return __uint_as_float(u & 0xffff0000u);
}

// ---------------- CSR build params ----------------
#define BSZ   64
#define NBUCK ((N_NODES + BSZ - 1) / BSZ)       // 782
#define NBP   1024
#define CAP   2560
#define EPB_A 8192
#define NBLK_A ((ETOT + EPB_A - 1) / EPB_A)     // 202
#define NCHUNK 25                                // src chunk = si>>11 (0..24)

// packed edge word: p = (di<<16) | si (both < 2^16)

// ---------------- K1: role-split fused kernel (r22 proven) ----------------
__global__ __launch_bounds__(256, 4) void fused_binA_gemm_kernel(
    const int* __restrict__ ei, uint_t* __restrict__ ebuf,
    int* __restrict__ cntm, int* __restrict__ offm,
    const float* __restrict__ x, const float* __restrict__ W,
    const float* __restrict__ att_src, const float* __restrict__ att_dst,
    ushort_t* __restrict__ hb, float* __restrict__ a_src,
    float* __restrict__ a_dst) {
  __shared__ uint_t lds[EPB_A + NBP + 8];   // 36.9 KB, roles alias
  const int tid = threadIdx.x;

  if (blockIdx.x < NBLK_A) {
    // ---------- binA2 role ----------
    uint_t* stage = lds;
    int* hist = (int*)(lds + EPB_A);
    int* wsum = hist + NBP;
    const int cb = blockIdx.x;
    const int e0 = cb * EPB_A;
    const int n = min(EPB_A, ETOT - e0);
    for (int i = tid; i < NBP; i += 256) hist[i] = 0;
    __syncthreads();
    for (int i = tid; i < n; i += 256) {
      int e = e0 + i;
      int si, di;
      if (e < E_EDGES) { si = ei[e]; di = ei[E_EDGES + e]; }
      else             { si = e - E_EDGES; di = si; }
      stage[i] = ((uint_t)di << 16) | (uint_t)si;
      atomicAdd(&hist[di >> 6], 1);
    }
    __syncthreads();
    const int ln = tid & 63, wv = tid >> 6;
    int c0 = hist[4 * tid], c1 = hist[4 * tid + 1];
    int c2 = hist[4 * tid + 2], c3 = hist[4 * tid + 3];
    int p1 = c0, p2 = c0 + c1, p3 = c0 + c1 + c2;
    int tot = p3 + c3;
    int xx = tot;
#pragma unroll
    for (int off = 1; off < 64; off <<= 1) {
      int y = __shfl_up(xx, off, 64);
      if (ln >= off) xx += y;
    }
    if (ln == 63) wsum[wv] = xx;
    __syncthreads();
    if (tid < 4) {
      int w = wsum[tid];
#pragma unroll
      for (int off = 1; off < 4; off <<= 1) {
        int y = __shfl_up(w, off, 64);
        if (tid >= off) w += y;
      }
      wsum[tid] = w;
    }
    __syncthreads();
    const int wo = (wv == 0) ? 0 : wsum[wv - 1];
    const int base = wo + xx - tot;
#pragma unroll
    for (int k = 0; k < 4; k++) {
      int idx = 4 * tid + k;
      int c = k == 0 ? c0 : k == 1 ? c1 : k == 2 ? c2 : c3;
      int o = base + (k == 0 ? 0 : k == 1 ? p1 : k == 2 ? p2 : p3);
      if (idx < NBUCK) {
        cntm[(size_t)cb * NBP + idx] = c;
        offm[(size_t)cb * NBP + idx] = o;
      }
      hist[idx] = o;
    }
    __syncthreads();
    for (int i = tid; i < n; i += 256) {
      uint_t p = stage[i];
      int pos = atomicAdd(&hist[p >> 22], 1);
      if (pos >= 0 && pos < n) ebuf[e0 + pos] = p;
    }
    return;
  }

  // ---------- gemm_att role (r15/r19 proven) ----------
  ushort_t* Ws = (ushort_t*)lds;   // 32 KB bf16
  const int gb = blockIdx.x - NBLK_A;
  const int wv = tid >> 6, l = tid & 63;
  const int lr = l & 15, lg = l >> 4;
  const int nbase = gb * 64 + wv * 16;
  int na = nbase + lr;
  if (na >= N_NODES) na = N_NODES - 1;
  const float* xrow = x + (size_t)na * DIN;

  float4 px[8];
#pragma unroll
  for (int kt = 0; kt < 4; kt++) {
    px[kt * 2]     = *(const float4*)&xrow[kt * 32 + lg * 8];
    px[kt * 2 + 1] = *(const float4*)&xrow[kt * 32 + lg * 8 + 4];
  }

  for (int u = tid; u < 2048; u += 256) {
    int row = u >> 4;
    float4 w0 = *(const float4*)&W[u * 8];
    float4 w1 = *(const float4*)&W[u * 8 + 4];
    uint4 pk;
    pk.x = (uint_t)f2bf(w0.x) | ((uint_t)f2bf(w0.y) << 16);
    pk.y = (uint_t)f2bf(w0.z) | ((uint_t)f2bf(w0.w) << 16);
    pk.z = (uint_t)f2bf(w1.x) | ((uint_t)f2bf(w1.y) << 16);
    pk.w = (uint_t)f2bf(w1.z) | ((uint_t)f2bf(w1.w) << 16);
    *(uint4*)&Ws[(u ^ (row & 7)) * 8] = pk;
  }
  __syncthreads();

  ffrag acc[8];
#pragma unroll
  for (int oc = 0; oc < 8; oc++) acc[oc] = (ffrag){0.f, 0.f, 0.f, 0.f};

#pragma unroll
  for (int kt = 0; kt < 4; kt++) {
    const float4 x0 = px[kt * 2];
    const float4 x1 = px[kt * 2 + 1];
    bfrag a;
    a[0] = (short)f2bf(x0.x); a[1] = (short)f2bf(x0.y);
    a[2] = (short)f2bf(x0.z); a[3] = (short)f2bf(x0.w);
    a[4] = (short)f2bf(x1.x); a[5] = (short)f2bf(x1.y);
    a[6] = (short)f2bf(x1.z); a[7] = (short)f2bf(x1.w);
#pragma unroll
    for (int oc = 0; oc < 8; oc++) {
      const int u = ((oc * 16 + lr) << 4) + kt * 4 + lg;
      const bfrag b = *(const bfrag*)&Ws[(u ^ (lr & 7)) * 8];
      acc[oc] = __builtin_amdgcn_mfma_f32_16x16x32_bf16(a, b, acc[oc], 0, 0, 0);
    }
  }

#pragma unroll
  for (int oc = 0; oc < 8; oc++) {
#pragma unroll
    for (int j = 0; j < 4; j++) {
      int n = nbase + lg * 4 + j;
      if (n < N_NODES)
        hb[((size_t)n << 7) + oc * 16 + lr] = f2bf(acc[oc][j]);
    }
  }

  float asv[8], adv[8];
#pragma unroll
  for (int oc = 0; oc < 8; oc++) {
    asv[oc] = att_src[oc * 16 + lr];
    adv[oc] = att_dst[oc * 16 + lr];
  }
#pragma unroll
  for (int j = 0; j < 4; j++) {
    float ps[4] = {0.f, 0.f, 0.f, 0.f};
    float pd[4] = {0.f, 0.f, 0.f, 0.f};
#pragma unroll
    for (int oc = 0; oc < 8; oc++) {
      ps[oc >> 1] = fmaf(acc[oc][j], asv[oc], ps[oc >> 1]);
      pd[oc >> 1] = fmaf(acc[oc][j], adv[oc], pd[oc >> 1]);
    }
#pragma unroll
    for (int off = 1; off < 16; off <<= 1) {
#pragma unroll
      for (int hd = 0; hd < 4; hd++) {
        ps[hd] += __shfl_xor(ps[hd], off);
        pd[hd] += __shfl_xor(pd[hd], off);
      }
    }
    int n = nbase + lg * 4 + j;
    if (n < N_NODES && lr < 4) {
      float vs = lr == 0 ? ps[0] : lr == 1 ? ps[1] : lr == 2 ? ps[2] : ps[3];
      float vd = lr == 0 ? pd[0] : lr == 1 ? pd[1] : lr == 2 ? pd[2] : pd[3];
      a_src[n * NH + lr] = vs;
      a_dst[n * NH + lr] = vd;
    }
  }
}

// ---------------- K2: per-bucket CSR build (r22 body; NCHUNK=25) ----------
__global__ __launch_bounds__(256) void binB_kernel(
    const uint_t* __restrict__ ebuf, const int* __restrict__ cntm,
    const int* __restrict__ offm,
    int* __restrict__ rs, int* __restrict__ re, ushort_t* __restrict__ col) {
  __shared__ uint_t el[CAP];
  __shared__ int cnt_l[BSZ * NCHUNK];
  __shared__ int roff_l[BSZ * NCHUNK];
  __shared__ int wsum[4];
  const int b = blockIdx.x;
  const int tid = threadIdx.x;
  const int ln = tid & 63, wv = tid >> 6;
  const int n0 = b << 6;
  const int nn = min(BSZ, N_NODES - n0);

  int c = (tid < NBLK_A) ? cntm[(size_t)tid * NBP + b] : 0;
  int o = (tid < NBLK_A) ? offm[(size_t)tid * NBP + b] : 0;
  int xx = c;
#pragma unroll
  for (int off = 1; off < 64; off <<= 1) {
    int y = __shfl_up(xx, off, 64);
    if (ln >= off) xx += y;
  }
  if (ln == 63) wsum[wv] = xx;
  __syncthreads();
  if (tid < 4) {
    int w = wsum[tid];
#pragma unroll
    for (int off = 1; off < 4; off <<= 1) {
      int y = __shfl_up(w, off, 64);
      if (tid >= off) w += y;
    }
    wsum[tid] = w;
  }
  __syncthreads();
  const int wo = (wv == 0) ? 0 : wsum[wv - 1];
  const int mystart = wo + xx - c;
  const int total0 = wsum[3];
  const int total = total0 < CAP ? total0 : CAP;
  if (tid < NBLK_A) {
    const uint_t* src = ebuf + (size_t)tid * EPB_A + o;
    for (int j = 0; j < c; j++) {
      int d = mystart + j;
      if (d < CAP) el[d] = src[j];
    }
  }
  for (int k = tid; k < BSZ * NCHUNK; k += 256) cnt_l[k] = 0;
  __syncthreads();

  for (int i = tid; i < total; i += 256) {
    uint_t p = el[i];
    int key = (int)((p >> 16) & 63) * NCHUNK + (int)((p & 0xFFFFu) >> 11);
    atomicAdd(&cnt_l[key], 1);
  }
  __syncthreads();
  if (tid < BSZ) {
    int pref[NCHUNK];
    int tot = 0;
#pragma unroll
    for (int k = 0; k < NCHUNK; k++) { pref[k] = tot; tot += cnt_l[tid * NCHUNK + k]; }
    int x2 = tot;
#pragma unroll
    for (int off = 1; off < 64; off <<= 1) {
      int y = __shfl_up(x2, off, 64);
      if (tid >= off) x2 += y;
    }
    const int nodebase = x2 - tot;
#pragma unroll
    for (int k = 0; k < NCHUNK; k++) roff_l[tid * NCHUNK + k] = nodebase + pref[k];
    if (tid < nn) {
      rs[n0 + tid] = b * CAP + nodebase;
      re[n0 + tid] = b * CAP + nodebase + tot;
    }
  }
  __syncthreads();
  for (int k = tid; k < BSZ * NCHUNK; k += 256) cnt_l[k] = 0;
  __syncthreads();
  for (int i = tid; i < total; i += 256) {
    uint_t p = el[i];
    int si = (int)(p & 0xFFFFu);
    int key = (int)((p >> 16) & 63) * NCHUNK + (si >> 11);
    int pos = atomicAdd(&cnt_l[key], 1);
    int q = b * CAP + roff_l[key] + pos;
    if (q >= 0 && q < NBUCK * CAP) col[q] = (ushort_t)si;
  }
}

// ---------------- K3: single-pass aggregation + prefetch (r22 proven) -----
#define NPB 16
#define CH  16

__global__ __launch_bounds__(256, 8) void agg_kernel(
    const ushort_t* __restrict__ col, const int* __restrict__ rs,
    const int* __restrict__ re, const ushort_t* __restrict__ hb,
    const float* __restrict__ a_src, const float* __restrict__ a_dst,
    float* __restrict__ out) {
  __shared__ float w_lds[NPB][CH][NH];
  __shared__ int   si_lds[NPB][CH];
  const int tid  = threadIdx.x;
  const int slot = tid >> 4;
  const int t    = tid & 15;
  const int node = blockIdx.x * NPB + slot;
  const int start = rs[node];
  const int deg   = re[node] - start;
  const float4 ad = *(const float4*)(a_dst + (size_t)node * NH);

  const int head = t >> 2;
  const int c8 = t << 3;
  const ushort_t* hc = hb + c8;
  float s = 0.f;
  float a0 = 0.f, a1 = 0.f, a2 = 0.f, a3 = 0.f;
  float a4 = 0.f, a5 = 0.f, a6 = 0.f, a7 = 0.f;
  float b0 = 0.f, b1 = 0.f, b2 = 0.f, b3 = 0.f;
  float b4 = 0.f, b5 = 0.f, b6 = 0.f, b7 = 0.f;

  int   si_c = 0;
  float4 as_c = make_float4(0.f, 0.f, 0.f, 0.f);
  if (t < deg) {
    si_c = col[start + t];
    si_c = si_c < N_NODES ? si_c : 0;
    as_c = *(const float4*)(a_src + (size_t)si_c * NH);
  }

  for (int base_e = 0; base_e < deg; base_e += CH) {
    int nch = deg - base_e;
    if (nch > CH) nch = CH;
    if (t < nch) {
      si_lds[slot][t] = si_c;
      float v0 = as_c.x + ad.x; v0 = v0 > 0.f ? v0 : 0.2f * v0;
      float v1 = as_c.y + ad.y; v1 = v1 > 0.f ? v1 : 0.2f * v1;
      float v2 = as_c.z + ad.z; v2 = v2 > 0.f ? v2 : 0.2f * v2;
      float v3 = as_c.w + ad.w; v3 = v3 > 0.f ? v3 : 0.2f * v3;
      w_lds[slot][t][0] = __expf(v0);
      w_lds[slot][t][1] = __expf(v1);
      w_lds[slot][t][2] = __expf(v2);
      w_lds[slot][t][3] = __expf(v3);
    }
    __builtin_amdgcn_fence(__ATOMIC_ACQ_REL, "wavefront");
    int nb = base_e + CH;
    if (nb + t < deg) {
      int sn = col[start + nb + t];
      sn = sn < N_NODES ? sn : 0;
      si_c = sn;
      as_c = *(const float4*)(a_src + (size_t)sn * NH);
    }
#pragma unroll 2
    for (int j = 0; j < nch; j++) {
      int si = si_lds[slot][j];
      float e = w_lds[slot][j][head];
      s += e;
      const uint4 hv = *(const uint4*)(hc + ((size_t)si << 7));
      float h0 = bf_lo(hv.x), h1 = bf_hi(hv.x);
      float h2 = bf_lo(hv.y), h3 = bf_hi(hv.y);
      float h4 = bf_lo(hv.z), h5 = bf_hi(hv.z);
      float h6 = bf_lo(hv.w), h7 = bf_hi(hv.w);
      a0 = fmaf(h0, e, a0); b0 += h0;
      a1 = fmaf(h1, e, a1); b1 += h1;
      a2 = fmaf(h2, e, a2); b2 += h2;
      a3 = fmaf(h3, e, a3); b3 += h3;
      a4 = fmaf(h4, e, a4); b4 += h4;
      a5 = fmaf(h5, e, a5); b5 += h5;
      a6 = fmaf(h6, e, a6); b6 += h6;
      a7 = fmaf(h7, e, a7); b7 += h7;
    }
    __builtin_amdgcn_fence(__ATOMIC_ACQ_REL, "wavefront");
  }
  const float inv = 1.0f / s;
  float* op = out + ((size_t)node << 7) + c8;
  *(float4*)(op)     = make_float4(fmaf(a0, inv, b0), fmaf(a1, inv, b1),
                                   fmaf(a2, inv, b2), fmaf(a3, inv, b3));
  *(float4*)(op + 4) = make_float4(fmaf(a4, inv, b4), fmaf(a5, inv, b5),
                                   fmaf(a6, inv, b6), fmaf(a7, inv, b7));
}

extern "C" void kernel_launch(void* const* d_in, const int* in_sizes, int n_in,
                              void* d_out, int out_size, void* d_ws, size_t ws_size,
                              hipStream_t stream) {
  const float* x       = (const float*)d_in[0];
  const int*   ei      = (const int*)d_in[1];
  const float* W       = (const float*)d_in[2];
  const float* att_src = (const float*)d_in[3];
  const float* att_dst = (const float*)d_in[4];
  float* out = (float*)d_out;

  // ws: hb | a_src | a_dst | cntm | offm | rs | re | col | ebuf
  ushort_t* hb = (ushort_t*)d_ws;
  float* a_src = (float*)(hb + (size_t)N_NODES * DOUT);
  float* a_dst = a_src + (size_t)N_NODES * NH;
  int* cntm    = (int*)(a_dst + (size_t)N_NODES * NH);    // NBLK_A*NBP
  int* offm    = cntm + (size_t)NBLK_A * NBP;             // NBLK_A*NBP
  int* rs      = offm + (size_t)NBLK_A * NBP;             // N_NODES
  int* re      = rs + N_NODES;                            // N_NODES
  ushort_t* col = (ushort_t*)(re + N_NODES);              // NBUCK*CAP
  uint_t* ebuf = (uint_t*)(col + (size_t)NBUCK * CAP);    // NBLK_A*EPB_A

  const int gemm_blocks = (N_NODES + 63) / 64;   // 782
  fused_binA_gemm_kernel<<<NBLK_A + gemm_blocks, 256, 0, stream>>>(
      ei, ebuf, cntm, offm, x, W, att_src, att_dst, hb, a_src, a_dst);
  binB_kernel<<<NBUCK, 256, 0, stream>>>(ebuf, cntm, offm, rs, re, col);
  agg_kernel<<<N_NODES / NPB, 256, 0, stream>>>(col, rs, re, hb, a_src, a_dst, out);
}